// Round 8
// baseline (163.351 us; speedup 1.0000x reference)
//
#include <hip/hip_runtime.h>
#include <math.h>

// Problem constants: B=1, C=64, D=H=W=16, HEADS=4, HD=16
#define CN   262144        // C * 4096 floats per [C, D, H, W] tensor

typedef __attribute__((ext_vector_type(8))) short short8;   // 8 bf16 (4 VGPRs)
typedef __attribute__((ext_vector_type(4))) float float4v;  // MFMA C/D

static __device__ __forceinline__ unsigned short f2bf(float f) {
    union { float f; unsigned u; } v; v.f = f;
    unsigned r = (v.u + 0x7FFFu + ((v.u >> 16) & 1u)) >> 16;   // RNE
    return (unsigned short)r;
}

// ---------------------------------------------------------------------------
// Stage 0: fuse conv_spec into qkv (weights only — exact linear reassociation):
//   Wf[oc][cj][t] = sum_ci w_qkv[oc][ci] * w_spec[ci][cj][t]
//   bf[oc]        = b_qkv[oc] + sum_ci w_qkv[oc][ci] * b_spec[ci]
__global__ __launch_bounds__(512) void wfuse_kernel(
        const float* __restrict__ w_spec, const float* __restrict__ b_spec,
        const float* __restrict__ w_qkv, const float* __restrict__ b_qkv,
        float* __restrict__ wf, float* __restrict__ bf) {
    int idx = blockIdx.x * 512 + threadIdx.x;   // 0..36863
    int oc = idx / 192;
    int r  = idx % 192;                          // = cj*3 + t (w_spec row layout)
    float s = 0.f;
    #pragma unroll 8
    for (int ci = 0; ci < 64; ++ci)
        s += w_qkv[oc * 64 + ci] * w_spec[ci * 192 + r];
    wf[oc * 192 + r] = s;
    if (idx < 192) {
        float t = b_qkv[idx];
        for (int ci = 0; ci < 64; ++ci) t += w_qkv[idx * 64 + ci] * b_spec[ci];
        bf[idx] = t;
    }
}

// ---------------------------------------------------------------------------
// Stage 1: spatial conv 3x3 over (H,W). pad (0,1,1).
// Block = (co, d): 1024 blocks x 512 thr; 8 waves split ci (8 each), LDS reduce.
__global__ __launch_bounds__(512) void conv_sp_kernel(
        const float* __restrict__ x, const float* __restrict__ w,
        const float* __restrict__ b, float* __restrict__ y) {
    __shared__ float ws[576];
    __shared__ float red[8][256];
    int co = blockIdx.x >> 4;
    int d  = blockIdx.x & 15;
    int tid = threadIdx.x;
    for (int idx = tid; idx < 576; idx += 512) ws[idx] = w[co * 576 + idx];
    __syncthreads();
    int og  = tid & 63;                 // output quad: h = og>>2, w-base = (og&3)*4
    int grp = tid >> 6;                 // ci group (0..7)
    int h = og >> 2, wq = og & 3;
    float ax = 0.f, ay = 0.f, az = 0.f, aw = 0.f;
    #pragma unroll 4
    for (int c2 = 0; c2 < 8; ++c2) {
        int ci = grp * 8 + c2;
        const float* row = x + ci * 4096 + d * 256;
        const float* wc  = ws + ci * 9;
        #pragma unroll
        for (int dh = 0; dh < 3; ++dh) {
            int hh = h + dh - 1;
            if (hh < 0 || hh > 15) continue;
            const float* r = row + hh * 16 + wq * 4;
            float4 q0 = *(const float4*)r;
            float lm = (wq > 0) ? r[-1] : 0.f;
            float rp = (wq < 3) ? r[4]  : 0.f;
            float wL = wc[dh * 3 + 0], wM = wc[dh * 3 + 1], wR = wc[dh * 3 + 2];
            ax += wL * lm   + wM * q0.x + wR * q0.y;
            ay += wL * q0.x + wM * q0.y + wR * q0.z;
            az += wL * q0.y + wM * q0.z + wR * q0.w;
            aw += wL * q0.z + wM * q0.w + wR * rp;
        }
    }
    float4 part = {ax, ay, az, aw};
    *(float4*)&red[grp][og * 4] = part;
    __syncthreads();
    if (tid < 256) {
        float s = b[co];
        #pragma unroll
        for (int g = 0; g < 8; ++g) s += red[g][tid];
        y[co * 4096 + d * 256 + tid] = s;
    }
}

// ---------------------------------------------------------------------------
// Stage 2+3 fused: 3-tap spectral conv + 1x1 QKV directly from y1 using
// precomputed Wf/bf. Block = (oc, d): 3072 blocks x 512 thr, 8-way ci split.
// Outputs bf16 MFMA-ready layouts (q pre-scaled 0.25):
//   qb/kb: [head][pos][d16];  vtb: [head][m][h>>1][dim][kappa32],
//   kappa = 8*(w>>2)+4*(h&1)+(w&3)
__global__ __launch_bounds__(512) void qkv_fused_kernel(
        const float* __restrict__ y1, const float* __restrict__ wf,
        const float* __restrict__ bf,
        unsigned short* __restrict__ qb, unsigned short* __restrict__ kb,
        unsigned short* __restrict__ vtb) {
    __shared__ float ws[192];
    __shared__ float red[8][256];
    int oc = blockIdx.x >> 4;           // 0..191
    int d  = blockIdx.x & 15;
    int tid = threadIdx.x;
    if (tid < 192) ws[tid] = wf[oc * 192 + tid];
    __syncthreads();
    int og  = tid & 63;
    int grp = tid >> 6;
    int p0 = d * 256 + og * 4;
    float ax = 0.f, ay = 0.f, az = 0.f, aw = 0.f;
    #pragma unroll 4
    for (int c2 = 0; c2 < 8; ++c2) {
        int ci = grp * 8 + c2;
        const float* base = y1 + ci * 4096 + p0;
        float w0 = ws[ci * 3], w1 = ws[ci * 3 + 1], w2 = ws[ci * 3 + 2];
        if (d > 0) {
            float4 a = *(const float4*)(base - 256);
            ax += w0 * a.x; ay += w0 * a.y; az += w0 * a.z; aw += w0 * a.w;
        }
        float4 m = *(const float4*)base;
        ax += w1 * m.x; ay += w1 * m.y; az += w1 * m.z; aw += w1 * m.w;
        if (d < 15) {
            float4 c = *(const float4*)(base + 256);
            ax += w2 * c.x; ay += w2 * c.y; az += w2 * c.z; aw += w2 * c.w;
        }
    }
    float4 part = {ax, ay, az, aw};
    *(float4*)&red[grp][og * 4] = part;
    __syncthreads();
    if (tid < 256) {
        float val = bf[oc];
        #pragma unroll
        for (int g = 0; g < 8; ++g) val += red[g][tid];
        int which = oc >> 6;            // 0=q 1=k 2=v
        int hd = oc & 63;
        int head = hd >> 4, dim = hd & 15;
        if (which == 0) val *= 0.25f;
        int p = d * 256 + tid;          // global position
        if (which == 2) {
            int h = (p >> 4) & 15, w0 = p & 15;
            int kap = 8 * (w0 >> 2) + 4 * (h & 1) + (w0 & 3);
            vtb[((head * 16 + d) * 8 + (h >> 1)) * 512 + dim * 32 + kap] = f2bf(val);
        } else {
            (which == 0 ? qb : kb)[head * 65536 + p * 16 + dim] = f2bf(val);
        }
    }
}

// ---------------------------------------------------------------------------
// Stage 4: retention attention via MFMA (unchanged — verified).
__global__ __launch_bounds__(512, 2) void attn_kernel(
        const unsigned short* __restrict__ qb, const unsigned short* __restrict__ kb,
        const unsigned short* __restrict__ vtb, const float* __restrict__ gamma,
        float* __restrict__ ao0, float* __restrict__ ao1,
        float* __restrict__ ao2, float* __restrict__ ao3) {
    __shared__ __align__(16) unsigned short ksh[4096];   // [n][o][d16] bf16, 8 KB
    __shared__ __align__(16) unsigned short vsh[4096];   // [np][dim][kappa32], 8 KB
    __shared__ float gp[32];
    int tid = threadIdx.x;
    int bI = blockIdx.x;
    int head = bI >> 7;                 // 4
    int mg   = (bI >> 5) & 3;           // 4 m-quarters
    int oct  = bI & 31;                 // 32 q-octets per head

    if (tid < 32) {
        float g = 1.f / (1.f + __expf(-gamma[0]));
        gp[tid] = __powf(g, (float)tid);
    }

    int wv = tid >> 6, lane = tid & 63;
    int quad = lane >> 4, l15 = lane & 15;
    int t = oct * 8 + wv;               // tile index 0..255 (= i*16 + j)
    int i = t >> 4, j = t & 15;

    short8 zero8 = {0, 0, 0, 0, 0, 0, 0, 0};
    float4v czero = {0.f, 0.f, 0.f, 0.f};

    // Q fragment (B operand): B[k=d][n=q]; zero for d>=16 (quads 2,3)
    short8 qf = zero8;
    if (quad < 2)
        qf = *(const short8*)(qb + head * 65536 + (t * 16 + l15) * 16 + quad * 8);

    __syncthreads();                    // gp ready
    float wd[4];
    #pragma unroll
    for (int r = 0; r < 4; ++r) wd[r] = gp[abs(l15 - (quad * 4 + r))];

    float4v O = czero;

    for (int mm = 0; mm < 4; ++mm) {
        int m = mg * 4 + mm;
        __syncthreads();                // previous slab fully consumed
        ((float4*)ksh)[tid] = ((const float4*)(kb  + head * 65536 + m * 4096))[tid];
        ((float4*)vsh)[tid] = ((const float4*)(vtb + (head * 16 + m) * 4096))[tid];
        __syncthreads();

        int eim = abs(i - m);
        #pragma unroll
        for (int np = 0; np < 8; ++np) {
            short8 a2 = zero8;
            #pragma unroll
            for (int s = 0; s < 2; ++s) {
                int n = np * 2 + s;
                short8 a1 = zero8;
                if (quad < 2)
                    a1 = *(const short8*)(ksh + n * 256 + l15 * 16 + quad * 8);
                float4v d1 = __builtin_amdgcn_mfma_f32_16x16x32_bf16(a1, qf, czero, 0, 0, 0);
                float smn = gp[eim + abs(j - n)];        // wave-uniform broadcast
                float e0 = __expf(d1[0] * smn * wd[0]);
                float e1 = __expf(d1[1] * smn * wd[1]);
                float e2 = __expf(d1[2] * smn * wd[2]);
                float e3 = __expf(d1[3] * smn * wd[3]);
                float sm = e0 + e1 + e2 + e3;
                sm += __shfl_xor(sm, 16);
                sm += __shfl_xor(sm, 32);
                float inv = __builtin_amdgcn_rcpf(sm);
                a2[s * 4 + 0] = (short)f2bf(e0 * inv);
                a2[s * 4 + 1] = (short)f2bf(e1 * inv);
                a2[s * 4 + 2] = (short)f2bf(e2 * inv);
                a2[s * 4 + 3] = (short)f2bf(e3 * inv);
            }
            short8 b2 = *(const short8*)(vsh + np * 512 + l15 * 32 + quad * 8);
            O = __builtin_amdgcn_mfma_f32_16x16x32_bf16(a2, b2, O, 0, 0, 0);
        }
    }

    // O: col=lane&15=dim, row=quad*4+reg=query-w. 4 consecutive positions.
    float* aop = (mg == 0) ? ao0 : ((mg == 1) ? ao1 : ((mg == 2) ? ao2 : ao3));
    float4 ov = {O[0], O[1], O[2], O[3]};
    *(float4*)(aop + (head * 16 + l15) * 4096 + t * 16 + quad * 4) = ov;
}

// ---------------------------------------------------------------------------
// Stage 5: 1x1x1 projection; sums four m-quarter partials.
// Block = (oc, d): 1024 blocks x 512 thr, 8-way ci split + LDS reduce.
__global__ __launch_bounds__(512) void proj_kernel(
        const float* __restrict__ ao0, const float* __restrict__ ao1,
        const float* __restrict__ ao2, const float* __restrict__ ao3,
        const float* __restrict__ w, const float* __restrict__ b,
        float* __restrict__ out) {
    __shared__ float ws[64];
    __shared__ float red[8][256];
    int oc = blockIdx.x >> 4;
    int d  = blockIdx.x & 15;
    int tid = threadIdx.x;
    if (tid < 64) ws[tid] = w[oc * 64 + tid];
    __syncthreads();
    int og  = tid & 63;
    int grp = tid >> 6;
    int p0 = d * 256 + og * 4;
    float ax = 0.f, ay = 0.f, az = 0.f, aw = 0.f;
    #pragma unroll 4
    for (int c2 = 0; c2 < 8; ++c2) {
        int ci = grp * 8 + c2;
        float  c = ws[ci];
        float4 a = *(const float4*)(ao0 + ci * 4096 + p0);
        float4 e = *(const float4*)(ao1 + ci * 4096 + p0);
        float4 f = *(const float4*)(ao2 + ci * 4096 + p0);
        float4 g = *(const float4*)(ao3 + ci * 4096 + p0);
        ax += c * (a.x + e.x + f.x + g.x);
        ay += c * (a.y + e.y + f.y + g.y);
        az += c * (a.z + e.z + f.z + g.z);
        aw += c * (a.w + e.w + f.w + g.w);
    }
    float4 part = {ax, ay, az, aw};
    *(float4*)&red[grp][og * 4] = part;
    __syncthreads();
    if (tid < 256) {
        float s = b[oc];
        #pragma unroll
        for (int g = 0; g < 8; ++g) s += red[g][tid];
        out[oc * 4096 + d * 256 + tid] = s;
    }
}

// ---------------------------------------------------------------------------
extern "C" void kernel_launch(void* const* d_in, const int* in_sizes, int n_in,
                              void* d_out, int out_size, void* d_ws, size_t ws_size,
                              hipStream_t stream) {
    const float* x      = (const float*)d_in[0];
    const float* gamma  = (const float*)d_in[1];
    const float* w_sp   = (const float*)d_in[2];
    const float* b_sp   = (const float*)d_in[3];
    const float* w_spec = (const float*)d_in[4];
    const float* b_spec = (const float*)d_in[5];
    const float* w_qkv  = (const float*)d_in[6];
    const float* b_qkv  = (const float*)d_in[7];
    const float* w_proj = (const float*)d_in[8];
    const float* b_proj = (const float*)d_in[9];
    float* out = (float*)d_out;

    float* ws = (float*)d_ws;
    float* y1  = ws;                         // [64][4096] f32; reused as ao0
    float* wf  = ws + CN;                    // [192][64][3] fused weights
    float* bf  = ws + CN + 40960;            // [192] fused bias
    unsigned short* qb  = (unsigned short*)(ws + 2 * CN);            // 512 KB bf16
    unsigned short* kb  = (unsigned short*)(ws + 2 * CN + CN / 2);   // 512 KB bf16
    unsigned short* vtb = (unsigned short*)(ws + 3 * CN);            // 512 KB bf16
    float* ao0 = y1;                         // safe: y1 consumed by qkv_fused
    float* ao1 = ws + 3 * CN + CN / 2;       // [64][4096] partial (m 4..7)
    float* ao2 = ws + 4 * CN + CN / 2;       // [64][4096] partial (m 8..11)
    float* ao3 = ws + 5 * CN + CN / 2;       // [64][4096] partial (m 12..15)

    wfuse_kernel    <<<  72, 512, 0, stream>>>(w_spec, b_spec, w_qkv, b_qkv, wf, bf);
    conv_sp_kernel  <<<1024, 512, 0, stream>>>(x, w_sp, b_sp, y1);
    qkv_fused_kernel<<<3072, 512, 0, stream>>>(y1, wf, bf, qb, kb, vtb);
    attn_kernel     <<< 512, 512, 0, stream>>>(qb, kb, vtb, gamma, ao0, ao1, ao2, ao3);
    proj_kernel     <<<1024, 512, 0, stream>>>(ao0, ao1, ao2, ao3, w_proj, b_proj, out);
}

// Round 9
// 147.016 us; speedup vs baseline: 1.1111x; 1.1111x over previous
//
#include <hip/hip_runtime.h>
#include <math.h>

// Problem constants: B=1, C=64, D=H=W=16, HEADS=4, HD=16
#define CN   262144        // C * 4096 floats per [C, D, H, W] tensor

typedef __attribute__((ext_vector_type(8))) short short8;   // 8 bf16 (4 VGPRs)
typedef __attribute__((ext_vector_type(4))) short short4v;  // 8 B
typedef __attribute__((ext_vector_type(4))) float float4v;  // MFMA C/D

static __device__ __forceinline__ unsigned short f2bf(float f) {
    union { float f; unsigned u; } v; v.f = f;
    unsigned r = (v.u + 0x7FFFu + ((v.u >> 16) & 1u)) >> 16;   // RNE
    return (unsigned short)r;
}

// ---------------------------------------------------------------------------
// Stage 0: fuse conv_spec into qkv (exact linear reassociation), emit bf16
// A-matrix wfb[oc][k=cj*3+t] with q-scale 0.25 folded into rows oc<64, plus
// fused f32 bias bfv[oc] (also q-scaled).
__global__ __launch_bounds__(512) void wfuse_kernel(
        const float* __restrict__ w_spec, const float* __restrict__ b_spec,
        const float* __restrict__ w_qkv, const float* __restrict__ b_qkv,
        unsigned short* __restrict__ wfb, float* __restrict__ bfv) {
    int idx = blockIdx.x * 512 + threadIdx.x;   // 0..36863
    int oc = idx / 192;
    int r  = idx % 192;                          // = cj*3 + t
    float s = 0.f;
    #pragma unroll 8
    for (int ci = 0; ci < 64; ++ci)
        s += w_qkv[oc * 64 + ci] * w_spec[ci * 192 + r];
    if (oc < 64) s *= 0.25f;
    wfb[oc * 192 + r] = f2bf(s);
    if (idx < 192) {
        float t = b_qkv[idx];
        for (int ci = 0; ci < 64; ++ci) t += w_qkv[idx * 64 + ci] * b_spec[ci];
        if (idx < 64) t *= 0.25f;
        bfv[idx] = t;
    }
}

// ---------------------------------------------------------------------------
// Stage 1: spatial conv 3x3 over (H,W). pad (0,1,1). (unchanged from r8)
__global__ __launch_bounds__(512) void conv_sp_kernel(
        const float* __restrict__ x, const float* __restrict__ w,
        const float* __restrict__ b, float* __restrict__ y) {
    __shared__ float ws[576];
    __shared__ float red[8][256];
    int co = blockIdx.x >> 4;
    int d  = blockIdx.x & 15;
    int tid = threadIdx.x;
    for (int idx = tid; idx < 576; idx += 512) ws[idx] = w[co * 576 + idx];
    __syncthreads();
    int og  = tid & 63;
    int grp = tid >> 6;
    int h = og >> 2, wq = og & 3;
    float ax = 0.f, ay = 0.f, az = 0.f, aw = 0.f;
    #pragma unroll 4
    for (int c2 = 0; c2 < 8; ++c2) {
        int ci = grp * 8 + c2;
        const float* row = x + ci * 4096 + d * 256;
        const float* wc  = ws + ci * 9;
        #pragma unroll
        for (int dh = 0; dh < 3; ++dh) {
            int hh = h + dh - 1;
            if (hh < 0 || hh > 15) continue;
            const float* r = row + hh * 16 + wq * 4;
            float4 q0 = *(const float4*)r;
            float lm = (wq > 0) ? r[-1] : 0.f;
            float rp = (wq < 3) ? r[4]  : 0.f;
            float wL = wc[dh * 3 + 0], wM = wc[dh * 3 + 1], wR = wc[dh * 3 + 2];
            ax += wL * lm   + wM * q0.x + wR * q0.y;
            ay += wL * q0.x + wM * q0.y + wR * q0.z;
            az += wL * q0.y + wM * q0.z + wR * q0.w;
            aw += wL * q0.z + wM * q0.w + wR * rp;
        }
    }
    float4 part = {ax, ay, az, aw};
    *(float4*)&red[grp][og * 4] = part;
    __syncthreads();
    if (tid < 256) {
        float s = b[co];
        #pragma unroll
        for (int g = 0; g < 8; ++g) s += red[g][tid];
        y[co * 4096 + d * 256 + tid] = s;
    }
}

// ---------------------------------------------------------------------------
// Stage 2+3: spectral-conv + QKV as MFMA GEMM. Per block: one (d, pos-half,
// oc-third): M=64, N=128, K=192 (ci x 3 taps, d-boundary zero-padded).
// y1 slab im2col'd to LDS ONCE (traffic 96 blocks x ~96KB reads ~ 6 MB vs
// 590 MB for the per-oc-block version). A (wfb) in registers.
// Epilogue writes bf16 q/k/v in attn-ready layouts.
#define BTP 196   // Bt row stride in bf16 (392 B: 8B-aligned, bank stride 2)
__global__ __launch_bounds__(512, 2) void qkv_mfma_kernel(
        const float* __restrict__ y1, const unsigned short* __restrict__ wfb,
        const float* __restrict__ bfv,
        unsigned short* __restrict__ qb, unsigned short* __restrict__ kb,
        unsigned short* __restrict__ vtb) {
    __shared__ __align__(16) unsigned short Bt[128 * BTP];   // [pos][k], 49 KB
    int bI  = blockIdx.x;            // 96 = 16 d x 2 ph x 3 ocg
    int ocg = bI % 3;                // 0=q 1=k 2=v
    int ph  = (bI / 3) & 1;
    int d   = bI / 6;
    int tid = threadIdx.x;

    // ---- stage im2col slab: Bt[px][ci*3+t] = y1[ci][d+t-1][ph*128+px]
    {
        int px  = tid & 127;
        int cig = tid >> 7;          // 0..3
        const float* yb = y1 + d * 256 + ph * 128 + px;
        for (int cc = 0; cc < 16; ++cc) {
            int ci = cig * 16 + cc;
            const float* yc = yb + ci * 4096;
            #pragma unroll
            for (int t = 0; t < 3; ++t) {
                float v = 0.f;
                if (!((d == 0 && t == 0) || (d == 15 && t == 2)))
                    v = yc[(t - 1) * 256];
                Bt[px * BTP + ci * 3 + t] = f2bf(v);
            }
        }
    }

    int wv = tid >> 6, lane = tid & 63;
    int quad = lane >> 4, l15 = lane & 15;
    int Mt = wv >> 1;                // 0..3 (= head)
    int nb = (wv & 1) * 4;           // N-tile base (4 tiles of 16 pos)

    // ---- A-fragments: wfb rows = oc, A[m=l15][k=quad*8+j], 6 K-steps
    short8 af[6];
    {
        const unsigned short* ab = wfb + (ocg * 64 + Mt * 16 + l15) * 192 + quad * 8;
        #pragma unroll
        for (int ks = 0; ks < 6; ++ks) af[ks] = *(const short8*)(ab + ks * 32);
    }
    float bias[4];
    #pragma unroll
    for (int r = 0; r < 4; ++r) bias[r] = bfv[ocg * 64 + Mt * 16 + quad * 4 + r];

    __syncthreads();

    float4v czero = {0.f, 0.f, 0.f, 0.f};
    float4v acc[4] = {czero, czero, czero, czero};
    #pragma unroll
    for (int nt = 0; nt < 4; ++nt) {
        const unsigned short* brow = Bt + ((nb + nt) * 16 + l15) * BTP + quad * 8;
        #pragma unroll
        for (int ks = 0; ks < 6; ++ks) {
            short4v lo = *(const short4v*)(brow + ks * 32);
            short4v hi = *(const short4v*)(brow + ks * 32 + 4);
            short8 bf8 = {lo[0], lo[1], lo[2], lo[3], hi[0], hi[1], hi[2], hi[3]};
            acc[nt] = __builtin_amdgcn_mfma_f32_16x16x32_bf16(af[ks], bf8, acc[nt], 0, 0, 0);
        }
    }

    // ---- epilogue: C row = oc_local (quad*4+r), col = pos (l15)
    #pragma unroll
    for (int nt = 0; nt < 4; ++nt) {
        int p = d * 256 + ph * 128 + (nb + nt) * 16 + l15;
        if (ocg == 2) {
            int h = (p >> 4) & 15, w0 = p & 15;
            int kap = 8 * (w0 >> 2) + 4 * (h & 1) + (w0 & 3);
            unsigned short* dst = vtb + ((Mt * 16 + d) * 8 + (h >> 1)) * 512
                                      + (quad * 4) * 32 + kap;
            #pragma unroll
            for (int r = 0; r < 4; ++r) dst[r * 32] = f2bf(acc[nt][r] + bias[r]);
        } else {
            unsigned short* dst = (ocg == 0 ? qb : kb) + Mt * 65536 + p * 16 + quad * 4;
            unsigned t0 = (unsigned)f2bf(acc[nt][0] + bias[0])
                        | ((unsigned)f2bf(acc[nt][1] + bias[1]) << 16);
            unsigned t1 = (unsigned)f2bf(acc[nt][2] + bias[2])
                        | ((unsigned)f2bf(acc[nt][3] + bias[3]) << 16);
            *(unsigned*)dst = t0;
            *(unsigned*)(dst + 2) = t1;
        }
    }
}

// ---------------------------------------------------------------------------
// Stage 4: retention attention via MFMA (unchanged — verified).
__global__ __launch_bounds__(512, 2) void attn_kernel(
        const unsigned short* __restrict__ qb, const unsigned short* __restrict__ kb,
        const unsigned short* __restrict__ vtb, const float* __restrict__ gamma,
        float* __restrict__ ao0, float* __restrict__ ao1,
        float* __restrict__ ao2, float* __restrict__ ao3) {
    __shared__ __align__(16) unsigned short ksh[4096];   // [n][o][d16] bf16, 8 KB
    __shared__ __align__(16) unsigned short vsh[4096];   // [np][dim][kappa32], 8 KB
    __shared__ float gp[32];
    int tid = threadIdx.x;
    int bI = blockIdx.x;
    int head = bI >> 7;                 // 4
    int mg   = (bI >> 5) & 3;           // 4 m-quarters
    int oct  = bI & 31;                 // 32 q-octets per head

    if (tid < 32) {
        float g = 1.f / (1.f + __expf(-gamma[0]));
        gp[tid] = __powf(g, (float)tid);
    }

    int wv = tid >> 6, lane = tid & 63;
    int quad = lane >> 4, l15 = lane & 15;
    int t = oct * 8 + wv;               // tile index 0..255 (= i*16 + j)
    int i = t >> 4, j = t & 15;

    short8 zero8 = {0, 0, 0, 0, 0, 0, 0, 0};
    float4v czero = {0.f, 0.f, 0.f, 0.f};

    short8 qf = zero8;
    if (quad < 2)
        qf = *(const short8*)(qb + head * 65536 + (t * 16 + l15) * 16 + quad * 8);

    __syncthreads();                    // gp ready
    float wd[4];
    #pragma unroll
    for (int r = 0; r < 4; ++r) wd[r] = gp[abs(l15 - (quad * 4 + r))];

    float4v O = czero;

    for (int mm = 0; mm < 4; ++mm) {
        int m = mg * 4 + mm;
        __syncthreads();                // previous slab fully consumed
        ((float4*)ksh)[tid] = ((const float4*)(kb  + head * 65536 + m * 4096))[tid];
        ((float4*)vsh)[tid] = ((const float4*)(vtb + (head * 16 + m) * 4096))[tid];
        __syncthreads();

        int eim = abs(i - m);
        #pragma unroll
        for (int np = 0; np < 8; ++np) {
            short8 a2 = zero8;
            #pragma unroll
            for (int s = 0; s < 2; ++s) {
                int n = np * 2 + s;
                short8 a1 = zero8;
                if (quad < 2)
                    a1 = *(const short8*)(ksh + n * 256 + l15 * 16 + quad * 8);
                float4v d1 = __builtin_amdgcn_mfma_f32_16x16x32_bf16(a1, qf, czero, 0, 0, 0);
                float smn = gp[eim + abs(j - n)];        // wave-uniform broadcast
                float e0 = __expf(d1[0] * smn * wd[0]);
                float e1 = __expf(d1[1] * smn * wd[1]);
                float e2 = __expf(d1[2] * smn * wd[2]);
                float e3 = __expf(d1[3] * smn * wd[3]);
                float sm = e0 + e1 + e2 + e3;
                sm += __shfl_xor(sm, 16);
                sm += __shfl_xor(sm, 32);
                float inv = __builtin_amdgcn_rcpf(sm);
                a2[s * 4 + 0] = (short)f2bf(e0 * inv);
                a2[s * 4 + 1] = (short)f2bf(e1 * inv);
                a2[s * 4 + 2] = (short)f2bf(e2 * inv);
                a2[s * 4 + 3] = (short)f2bf(e3 * inv);
            }
            short8 b2 = *(const short8*)(vsh + np * 512 + l15 * 32 + quad * 8);
            O = __builtin_amdgcn_mfma_f32_16x16x32_bf16(a2, b2, O, 0, 0, 0);
        }
    }

    float* aop = (mg == 0) ? ao0 : ((mg == 1) ? ao1 : ((mg == 2) ? ao2 : ao3));
    float4 ov = {O[0], O[1], O[2], O[3]};
    *(float4*)(aop + (head * 16 + l15) * 4096 + t * 16 + quad * 4) = ov;
}

// ---------------------------------------------------------------------------
// Stage 5: projection as MFMA GEMM. Block = (d, pos-eighth of 32): M=64,
// N=32, K=64. The four m-quarter partials are summed during LDS staging.
// Traffic: 128 blocks x 32 KB = 4 MB (was 262 MB).
#define PTP 68    // Bt row stride bf16 (136 B: 8B-aligned)
__global__ __launch_bounds__(128) void proj_mfma_kernel(
        const float* __restrict__ ao0, const float* __restrict__ ao1,
        const float* __restrict__ ao2, const float* __restrict__ ao3,
        const float* __restrict__ w, const float* __restrict__ b,
        float* __restrict__ out) {
    __shared__ __align__(16) unsigned short Bt[32 * PTP];    // [pos][ci], 4.4 KB
    int d  = blockIdx.x >> 3;
    int p8 = blockIdx.x & 7;
    int tid = threadIdx.x;               // 128

    {   // stage: sum 4 partials -> bf16 Bt[px][ci]
        int px = tid & 31, cig = tid >> 5;       // cig 0..3
        int gbase = d * 256 + p8 * 32 + px;
        for (int cc = 0; cc < 16; ++cc) {
            int ci = cig * 16 + cc;
            int ga = ci * 4096 + gbase;
            float v = ao0[ga] + ao1[ga] + ao2[ga] + ao3[ga];
            Bt[px * PTP + ci] = f2bf(v);
        }
    }
    __syncthreads();

    int wv = tid >> 6, lane = tid & 63;
    int quad = lane >> 4, l15 = lane & 15;
    float4v czero = {0.f, 0.f, 0.f, 0.f};
    float4v acc[2][2] = {{czero, czero}, {czero, czero}};

    #pragma unroll
    for (int mi = 0; mi < 2; ++mi) {
        int Mt = wv * 2 + mi;
        short8 af[2];
        const float* wsrc = w + (Mt * 16 + l15) * 64 + quad * 8;
        #pragma unroll
        for (int ks = 0; ks < 2; ++ks) {
            float4 wa = *(const float4*)(wsrc + ks * 32);
            float4 wb = *(const float4*)(wsrc + ks * 32 + 4);
            short8 a8 = {(short)f2bf(wa.x), (short)f2bf(wa.y), (short)f2bf(wa.z),
                         (short)f2bf(wa.w), (short)f2bf(wb.x), (short)f2bf(wb.y),
                         (short)f2bf(wb.z), (short)f2bf(wb.w)};
            af[ks] = a8;
        }
        #pragma unroll
        for (int nt = 0; nt < 2; ++nt) {
            const unsigned short* brow = Bt + (nt * 16 + l15) * PTP + quad * 8;
            #pragma unroll
            for (int ks = 0; ks < 2; ++ks) {
                short4v lo = *(const short4v*)(brow + ks * 32);
                short4v hi = *(const short4v*)(brow + ks * 32 + 4);
                short8 bf8 = {lo[0], lo[1], lo[2], lo[3], hi[0], hi[1], hi[2], hi[3]};
                acc[mi][nt] = __builtin_amdgcn_mfma_f32_16x16x32_bf16(af[ks], bf8, acc[mi][nt], 0, 0, 0);
            }
        }
    }

    #pragma unroll
    for (int mi = 0; mi < 2; ++mi) {
        #pragma unroll
        for (int nt = 0; nt < 2; ++nt) {
            int p = d * 256 + p8 * 32 + nt * 16 + l15;
            #pragma unroll
            for (int r = 0; r < 4; ++r) {
                int oc = (wv * 2 + mi) * 16 + quad * 4 + r;
                out[oc * 4096 + p] = acc[mi][nt][r] + b[oc];
            }
        }
    }
}

// ---------------------------------------------------------------------------
extern "C" void kernel_launch(void* const* d_in, const int* in_sizes, int n_in,
                              void* d_out, int out_size, void* d_ws, size_t ws_size,
                              hipStream_t stream) {
    const float* x      = (const float*)d_in[0];
    const float* gamma  = (const float*)d_in[1];
    const float* w_sp   = (const float*)d_in[2];
    const float* b_sp   = (const float*)d_in[3];
    const float* w_spec = (const float*)d_in[4];
    const float* b_spec = (const float*)d_in[5];
    const float* w_qkv  = (const float*)d_in[6];
    const float* b_qkv  = (const float*)d_in[7];
    const float* w_proj = (const float*)d_in[8];
    const float* b_proj = (const float*)d_in[9];
    float* out = (float*)d_out;

    float* ws = (float*)d_ws;
    float* y1  = ws;                         // [64][4096] f32; reused as ao0
    unsigned short* wfb = (unsigned short*)(ws + CN);   // [192][192] bf16
    float* bfv = ws + CN + 20480;            // [192] fused bias f32
    unsigned short* qb  = (unsigned short*)(ws + 2 * CN);            // 512 KB bf16
    unsigned short* kb  = (unsigned short*)(ws + 2 * CN + CN / 2);   // 512 KB bf16
    unsigned short* vtb = (unsigned short*)(ws + 3 * CN);            // 512 KB bf16
    float* ao0 = y1;                         // safe: y1 consumed by qkv_mfma
    float* ao1 = ws + 3 * CN + CN / 2;       // [64][4096] partial (m 4..7)
    float* ao2 = ws + 4 * CN + CN / 2;       // [64][4096] partial (m 8..11)
    float* ao3 = ws + 5 * CN + CN / 2;       // [64][4096] partial (m 12..15)

    wfuse_kernel    <<<  72, 512, 0, stream>>>(w_spec, b_spec, w_qkv, b_qkv, wfb, bfv);
    conv_sp_kernel  <<<1024, 512, 0, stream>>>(x, w_sp, b_sp, y1);
    qkv_mfma_kernel <<<  96, 512, 0, stream>>>(y1, wfb, bfv, qb, kb, vtb);
    attn_kernel     <<< 512, 512, 0, stream>>>(qb, kb, vtb, gamma, ao0, ao1, ao2, ao3);
    proj_mfma_kernel<<< 128, 128, 0, stream>>>(ao0, ao1, ao2, ao3, w_proj, b_proj, out);
}

// Round 10
// 142.895 us; speedup vs baseline: 1.1432x; 1.0288x over previous
//
#include <hip/hip_runtime.h>
#include <math.h>

// Problem constants: B=1, C=64, D=H=W=16, HEADS=4, HD=16
#define CN   262144        // C * 4096 floats per [C, D, H, W] tensor

typedef __attribute__((ext_vector_type(8))) short short8;   // 8 bf16 (4 VGPRs)
typedef __attribute__((ext_vector_type(4))) short short4v;  // 8 B
typedef __attribute__((ext_vector_type(4))) float float4v;  // MFMA C/D

static __device__ __forceinline__ unsigned short f2bf(float f) {
    union { float f; unsigned u; } v; v.f = f;
    unsigned r = (v.u + 0x7FFFu + ((v.u >> 16) & 1u)) >> 16;   // RNE
    return (unsigned short)r;
}

// ---------------------------------------------------------------------------
// Stage 0: fuse conv_spec into qkv (exact linear reassociation), emit bf16
// A-matrix wfb[oc][k=cj*3+t] with q-scale 0.25 folded into rows oc<64, plus
// fused f32 bias bfv[oc] (also q-scaled).
__global__ __launch_bounds__(512) void wfuse_kernel(
        const float* __restrict__ w_spec, const float* __restrict__ b_spec,
        const float* __restrict__ w_qkv, const float* __restrict__ b_qkv,
        unsigned short* __restrict__ wfb, float* __restrict__ bfv) {
    int idx = blockIdx.x * 512 + threadIdx.x;   // 0..36863
    int oc = idx / 192;
    int r  = idx % 192;                          // = cj*3 + t
    float s = 0.f;
    #pragma unroll 8
    for (int ci = 0; ci < 64; ++ci)
        s += w_qkv[oc * 64 + ci] * w_spec[ci * 192 + r];
    if (oc < 64) s *= 0.25f;
    wfb[oc * 192 + r] = f2bf(s);
    if (idx < 192) {
        float t = b_qkv[idx];
        for (int ci = 0; ci < 64; ++ci) t += w_qkv[idx * 64 + ci] * b_spec[ci];
        if (idx < 64) t *= 0.25f;
        bfv[idx] = t;
    }
}

// ---------------------------------------------------------------------------
// Stage 1: spatial conv 3x3 over (H,W). pad (0,1,1). (unchanged — 32 waves/CU)
__global__ __launch_bounds__(512) void conv_sp_kernel(
        const float* __restrict__ x, const float* __restrict__ w,
        const float* __restrict__ b, float* __restrict__ y) {
    __shared__ float ws[576];
    __shared__ float red[8][256];
    int co = blockIdx.x >> 4;
    int d  = blockIdx.x & 15;
    int tid = threadIdx.x;
    for (int idx = tid; idx < 576; idx += 512) ws[idx] = w[co * 576 + idx];
    __syncthreads();
    int og  = tid & 63;
    int grp = tid >> 6;
    int h = og >> 2, wq = og & 3;
    float ax = 0.f, ay = 0.f, az = 0.f, aw = 0.f;
    #pragma unroll 4
    for (int c2 = 0; c2 < 8; ++c2) {
        int ci = grp * 8 + c2;
        const float* row = x + ci * 4096 + d * 256;
        const float* wc  = ws + ci * 9;
        #pragma unroll
        for (int dh = 0; dh < 3; ++dh) {
            int hh = h + dh - 1;
            if (hh < 0 || hh > 15) continue;
            const float* r = row + hh * 16 + wq * 4;
            float4 q0 = *(const float4*)r;
            float lm = (wq > 0) ? r[-1] : 0.f;
            float rp = (wq < 3) ? r[4]  : 0.f;
            float wL = wc[dh * 3 + 0], wM = wc[dh * 3 + 1], wR = wc[dh * 3 + 2];
            ax += wL * lm   + wM * q0.x + wR * q0.y;
            ay += wL * q0.x + wM * q0.y + wR * q0.z;
            az += wL * q0.y + wM * q0.z + wR * q0.w;
            aw += wL * q0.z + wM * q0.w + wR * rp;
        }
    }
    float4 part = {ax, ay, az, aw};
    *(float4*)&red[grp][og * 4] = part;
    __syncthreads();
    if (tid < 256) {
        float s = b[co];
        #pragma unroll
        for (int g = 0; g < 8; ++g) s += red[g][tid];
        y[co * 4096 + d * 256 + tid] = s;
    }
}

// ---------------------------------------------------------------------------
// Stage 2+3: spectral-conv + QKV as MFMA GEMM.
// Block = (d, pos-quarter, oc-third): 192 blocks. M=64, N=64, K=192.
// Staging: 24 loads/thread (was 48); LDS 24.5 KB (was 49).
#define BTP 196   // Bt row stride in bf16 (392 B: 8B-aligned)
__global__ __launch_bounds__(512, 2) void qkv_mfma_kernel(
        const float* __restrict__ y1, const unsigned short* __restrict__ wfb,
        const float* __restrict__ bfv,
        unsigned short* __restrict__ qb, unsigned short* __restrict__ kb,
        unsigned short* __restrict__ vtb) {
    __shared__ __align__(16) unsigned short Bt[64 * BTP];    // [pos][k], 24.5 KB
    int bI  = blockIdx.x;            // 192 = 16 d x 4 pq x 3 ocg
    int ocg = bI % 3;                // 0=q 1=k 2=v
    int pq  = (bI / 3) & 3;
    int d   = bI / 12;
    int tid = threadIdx.x;

    // ---- stage im2col slab: Bt[px][ci*3+t] = y1[ci][d+t-1][pq*64+px]
    {
        int px  = tid & 63;
        int cig = tid >> 6;          // 0..7 (8 ci each)
        const float* yb = y1 + d * 256 + pq * 64 + px;
        #pragma unroll 2
        for (int cc = 0; cc < 8; ++cc) {
            int ci = cig * 8 + cc;
            const float* yc = yb + ci * 4096;
            #pragma unroll
            for (int t = 0; t < 3; ++t) {
                float v = 0.f;
                if (!((d == 0 && t == 0) || (d == 15 && t == 2)))
                    v = yc[(t - 1) * 256];
                Bt[px * BTP + ci * 3 + t] = f2bf(v);
            }
        }
    }

    int wv = tid >> 6, lane = tid & 63;
    int quad = lane >> 4, l15 = lane & 15;
    int Mt = wv >> 1;                // 0..3 (= head)
    int nb = (wv & 1) * 2;           // N-tile base (2 tiles of 16 pos)

    // ---- A-fragments: A[m=l15][k=quad*8+j], 6 K-steps
    short8 af[6];
    {
        const unsigned short* ab = wfb + (ocg * 64 + Mt * 16 + l15) * 192 + quad * 8;
        #pragma unroll
        for (int ks = 0; ks < 6; ++ks) af[ks] = *(const short8*)(ab + ks * 32);
    }
    float bias[4];
    #pragma unroll
    for (int r = 0; r < 4; ++r) bias[r] = bfv[ocg * 64 + Mt * 16 + quad * 4 + r];

    __syncthreads();

    float4v czero = {0.f, 0.f, 0.f, 0.f};
    float4v acc[2] = {czero, czero};
    #pragma unroll
    for (int nt = 0; nt < 2; ++nt) {
        const unsigned short* brow = Bt + ((nb + nt) * 16 + l15) * BTP + quad * 8;
        #pragma unroll
        for (int ks = 0; ks < 6; ++ks) {
            short4v lo = *(const short4v*)(brow + ks * 32);
            short4v hi = *(const short4v*)(brow + ks * 32 + 4);
            short8 bf8 = {lo[0], lo[1], lo[2], lo[3], hi[0], hi[1], hi[2], hi[3]};
            acc[nt] = __builtin_amdgcn_mfma_f32_16x16x32_bf16(af[ks], bf8, acc[nt], 0, 0, 0);
        }
    }

    // ---- epilogue: C row = oc_local (quad*4+r), col = pos (l15)
    #pragma unroll
    for (int nt = 0; nt < 2; ++nt) {
        int p = d * 256 + pq * 64 + (nb + nt) * 16 + l15;
        if (ocg == 2) {
            int h = (p >> 4) & 15, w0 = p & 15;
            int kap = 8 * (w0 >> 2) + 4 * (h & 1) + (w0 & 3);
            unsigned short* dst = vtb + ((Mt * 16 + d) * 8 + (h >> 1)) * 512
                                      + (quad * 4) * 32 + kap;
            #pragma unroll
            for (int r = 0; r < 4; ++r) dst[r * 32] = f2bf(acc[nt][r] + bias[r]);
        } else {
            unsigned short* dst = (ocg == 0 ? qb : kb) + Mt * 65536 + p * 16 + quad * 4;
            unsigned t0 = (unsigned)f2bf(acc[nt][0] + bias[0])
                        | ((unsigned)f2bf(acc[nt][1] + bias[1]) << 16);
            unsigned t1 = (unsigned)f2bf(acc[nt][2] + bias[2])
                        | ((unsigned)f2bf(acc[nt][3] + bias[3]) << 16);
            *(unsigned*)dst = t0;
            *(unsigned*)(dst + 2) = t1;
        }
    }
}

// ---------------------------------------------------------------------------
// Stage 4: retention attention via MFMA (unchanged — verified).
__global__ __launch_bounds__(512, 2) void attn_kernel(
        const unsigned short* __restrict__ qb, const unsigned short* __restrict__ kb,
        const unsigned short* __restrict__ vtb, const float* __restrict__ gamma,
        float* __restrict__ ao0, float* __restrict__ ao1,
        float* __restrict__ ao2, float* __restrict__ ao3) {
    __shared__ __align__(16) unsigned short ksh[4096];   // [n][o][d16] bf16, 8 KB
    __shared__ __align__(16) unsigned short vsh[4096];   // [np][dim][kappa32], 8 KB
    __shared__ float gp[32];
    int tid = threadIdx.x;
    int bI = blockIdx.x;
    int head = bI >> 7;                 // 4
    int mg   = (bI >> 5) & 3;           // 4 m-quarters
    int oct  = bI & 31;                 // 32 q-octets per head

    if (tid < 32) {
        float g = 1.f / (1.f + __expf(-gamma[0]));
        gp[tid] = __powf(g, (float)tid);
    }

    int wv = tid >> 6, lane = tid & 63;
    int quad = lane >> 4, l15 = lane & 15;
    int t = oct * 8 + wv;               // tile index 0..255 (= i*16 + j)
    int i = t >> 4, j = t & 15;

    short8 zero8 = {0, 0, 0, 0, 0, 0, 0, 0};
    float4v czero = {0.f, 0.f, 0.f, 0.f};

    short8 qf = zero8;
    if (quad < 2)
        qf = *(const short8*)(qb + head * 65536 + (t * 16 + l15) * 16 + quad * 8);

    __syncthreads();                    // gp ready
    float wd[4];
    #pragma unroll
    for (int r = 0; r < 4; ++r) wd[r] = gp[abs(l15 - (quad * 4 + r))];

    float4v O = czero;

    for (int mm = 0; mm < 4; ++mm) {
        int m = mg * 4 + mm;
        __syncthreads();                // previous slab fully consumed
        ((float4*)ksh)[tid] = ((const float4*)(kb  + head * 65536 + m * 4096))[tid];
        ((float4*)vsh)[tid] = ((const float4*)(vtb + (head * 16 + m) * 4096))[tid];
        __syncthreads();

        int eim = abs(i - m);
        #pragma unroll
        for (int np = 0; np < 8; ++np) {
            short8 a2 = zero8;
            #pragma unroll
            for (int s = 0; s < 2; ++s) {
                int n = np * 2 + s;
                short8 a1 = zero8;
                if (quad < 2)
                    a1 = *(const short8*)(ksh + n * 256 + l15 * 16 + quad * 8);
                float4v d1 = __builtin_amdgcn_mfma_f32_16x16x32_bf16(a1, qf, czero, 0, 0, 0);
                float smn = gp[eim + abs(j - n)];        // wave-uniform broadcast
                float e0 = __expf(d1[0] * smn * wd[0]);
                float e1 = __expf(d1[1] * smn * wd[1]);
                float e2 = __expf(d1[2] * smn * wd[2]);
                float e3 = __expf(d1[3] * smn * wd[3]);
                float sm = e0 + e1 + e2 + e3;
                sm += __shfl_xor(sm, 16);
                sm += __shfl_xor(sm, 32);
                float inv = __builtin_amdgcn_rcpf(sm);
                a2[s * 4 + 0] = (short)f2bf(e0 * inv);
                a2[s * 4 + 1] = (short)f2bf(e1 * inv);
                a2[s * 4 + 2] = (short)f2bf(e2 * inv);
                a2[s * 4 + 3] = (short)f2bf(e3 * inv);
            }
            short8 b2 = *(const short8*)(vsh + np * 512 + l15 * 32 + quad * 8);
            O = __builtin_amdgcn_mfma_f32_16x16x32_bf16(a2, b2, O, 0, 0, 0);
        }
    }

    float* aop = (mg == 0) ? ao0 : ((mg == 1) ? ao1 : ((mg == 2) ? ao2 : ao3));
    float4 ov = {O[0], O[1], O[2], O[3]};
    *(float4*)(aop + (head * 16 + l15) * 4096 + t * 16 + quad * 4) = ov;
}

// ---------------------------------------------------------------------------
// Stage 5: projection as MFMA GEMM. Block = (d, pos-16th): 256 blocks x 256
// thr. M=64, N=16, K=64. Partials summed during staging (16 loads/thread).
#define PTP 68    // Bt row stride bf16 (136 B: 8B-aligned)
__global__ __launch_bounds__(256) void proj_mfma_kernel(
        const float* __restrict__ ao0, const float* __restrict__ ao1,
        const float* __restrict__ ao2, const float* __restrict__ ao3,
        const float* __restrict__ w, const float* __restrict__ b,
        float* __restrict__ out) {
    __shared__ __align__(16) unsigned short Bt[16 * PTP];    // [pos][ci], 2.2 KB
    int d   = blockIdx.x >> 4;
    int p16 = blockIdx.x & 15;
    int tid = threadIdx.x;               // 256

    {   // stage: sum 4 partials -> bf16 Bt[px][ci]
        int px = tid & 15, cig = tid >> 4;        // cig 0..15 (4 ci each)
        int gbase = d * 256 + p16 * 16 + px;
        #pragma unroll
        for (int cc = 0; cc < 4; ++cc) {
            int ci = cig * 4 + cc;
            int ga = ci * 4096 + gbase;
            float v = ao0[ga] + ao1[ga] + ao2[ga] + ao3[ga];
            Bt[px * PTP + ci] = f2bf(v);
        }
    }
    __syncthreads();

    int wv = tid >> 6, lane = tid & 63;  // 4 waves: wv = M-tile
    int quad = lane >> 4, l15 = lane & 15;
    float4v czero = {0.f, 0.f, 0.f, 0.f};
    float4v acc = czero;

    short8 af[2];
    const float* wsrc = w + (wv * 16 + l15) * 64 + quad * 8;
    #pragma unroll
    for (int ks = 0; ks < 2; ++ks) {
        float4 wa = *(const float4*)(wsrc + ks * 32);
        float4 wb = *(const float4*)(wsrc + ks * 32 + 4);
        short8 a8 = {(short)f2bf(wa.x), (short)f2bf(wa.y), (short)f2bf(wa.z),
                     (short)f2bf(wa.w), (short)f2bf(wb.x), (short)f2bf(wb.y),
                     (short)f2bf(wb.z), (short)f2bf(wb.w)};
        af[ks] = a8;
    }
    const unsigned short* brow = Bt + l15 * PTP + quad * 8;
    #pragma unroll
    for (int ks = 0; ks < 2; ++ks) {
        short4v lo = *(const short4v*)(brow + ks * 32);
        short4v hi = *(const short4v*)(brow + ks * 32 + 4);
        short8 bf8 = {lo[0], lo[1], lo[2], lo[3], hi[0], hi[1], hi[2], hi[3]};
        acc = __builtin_amdgcn_mfma_f32_16x16x32_bf16(af[ks], bf8, acc, 0, 0, 0);
    }

    int p = d * 256 + p16 * 16 + l15;
    #pragma unroll
    for (int r = 0; r < 4; ++r) {
        int oc = wv * 16 + quad * 4 + r;
        out[oc * 4096 + p] = acc[r] + b[oc];
    }
}

// ---------------------------------------------------------------------------
extern "C" void kernel_launch(void* const* d_in, const int* in_sizes, int n_in,
                              void* d_out, int out_size, void* d_ws, size_t ws_size,
                              hipStream_t stream) {
    const float* x      = (const float*)d_in[0];
    const float* gamma  = (const float*)d_in[1];
    const float* w_sp   = (const float*)d_in[2];
    const float* b_sp   = (const float*)d_in[3];
    const float* w_spec = (const float*)d_in[4];
    const float* b_spec = (const float*)d_in[5];
    const float* w_qkv  = (const float*)d_in[6];
    const float* b_qkv  = (const float*)d_in[7];
    const float* w_proj = (const float*)d_in[8];
    const float* b_proj = (const float*)d_in[9];
    float* out = (float*)d_out;

    float* ws = (float*)d_ws;
    float* y1  = ws;                         // [64][4096] f32; reused as ao0
    unsigned short* wfb = (unsigned short*)(ws + CN);   // [192][192] bf16
    float* bfv = ws + CN + 20480;            // [192] fused bias f32
    unsigned short* qb  = (unsigned short*)(ws + 2 * CN);            // 512 KB bf16
    unsigned short* kb  = (unsigned short*)(ws + 2 * CN + CN / 2);   // 512 KB bf16
    unsigned short* vtb = (unsigned short*)(ws + 3 * CN);            // 512 KB bf16
    float* ao0 = y1;                         // safe: y1 consumed by qkv_mfma
    float* ao1 = ws + 3 * CN + CN / 2;       // [64][4096] partial (m 4..7)
    float* ao2 = ws + 4 * CN + CN / 2;       // [64][4096] partial (m 8..11)
    float* ao3 = ws + 5 * CN + CN / 2;       // [64][4096] partial (m 12..15)

    wfuse_kernel    <<<  72, 512, 0, stream>>>(w_spec, b_spec, w_qkv, b_qkv, wfb, bfv);
    conv_sp_kernel  <<<1024, 512, 0, stream>>>(x, w_sp, b_sp, y1);
    qkv_mfma_kernel <<< 192, 512, 0, stream>>>(y1, wfb, bfv, qb, kb, vtb);
    attn_kernel     <<< 512, 512, 0, stream>>>(qb, kb, vtb, gamma, ao0, ao1, ao2, ao3);
    proj_mfma_kernel<<< 256, 256, 0, stream>>>(ao0, ao1, ao2, ao3, w_proj, b_proj, out);
}

// Round 11
// 133.560 us; speedup vs baseline: 1.2231x; 1.0699x over previous
//
#include <hip/hip_runtime.h>
#include <math.h>

// Problem constants: B=1, C=64, D=H=W=16, HEADS=4, HD=16
#define CN   262144        // C * 4096 floats per [C, D, H, W] tensor

typedef __attribute__((ext_vector_type(8))) short short8;   // 8 bf16 (4 VGPRs)
typedef __attribute__((ext_vector_type(4))) short short4v;  // 8 B
typedef __attribute__((ext_vector_type(4))) float float4v;  // MFMA C/D

static __device__ __forceinline__ unsigned short f2bf(float f) {
    union { float f; unsigned u; } v; v.f = f;
    unsigned r = (v.u + 0x7FFFu + ((v.u >> 16) & 1u)) >> 16;   // RNE
    return (unsigned short)r;
}

// ---------------------------------------------------------------------------
// Stage 0+1 merged dispatch. Blocks 0..1023: spatial conv 3x3 (H,W), pad
// (0,1,1), block=(co,d), 8-way ci split + LDS reduce. Blocks 1024..1095:
// wfuse — conv_spec folded into qkv weights (exact linear reassociation):
//   wfb[oc][k=cj*3+t] bf16 (q rows pre-scaled 0.25), bfv[oc] f32 bias.
__global__ __launch_bounds__(512) void conv_sp_wfuse_kernel(
        const float* __restrict__ x, const float* __restrict__ w,
        const float* __restrict__ b, float* __restrict__ y,
        const float* __restrict__ w_spec, const float* __restrict__ b_spec,
        const float* __restrict__ w_qkv, const float* __restrict__ b_qkv,
        unsigned short* __restrict__ wfb, float* __restrict__ bfv) {
    if (blockIdx.x >= 1024) {
        int idx = (blockIdx.x - 1024) * 512 + threadIdx.x;   // 0..36863
        int oc = idx / 192;
        int r  = idx % 192;                                  // = cj*3 + t
        float s = 0.f;
        #pragma unroll 8
        for (int ci = 0; ci < 64; ++ci)
            s += w_qkv[oc * 64 + ci] * w_spec[ci * 192 + r];
        if (oc < 64) s *= 0.25f;
        wfb[oc * 192 + r] = f2bf(s);
        if (idx < 192) {
            float t = b_qkv[idx];
            for (int ci = 0; ci < 64; ++ci) t += w_qkv[idx * 64 + ci] * b_spec[ci];
            if (idx < 64) t *= 0.25f;
            bfv[idx] = t;
        }
        return;
    }
    __shared__ float ws[576];
    __shared__ float red[8][256];
    int co = blockIdx.x >> 4;
    int d  = blockIdx.x & 15;
    int tid = threadIdx.x;
    for (int idx = tid; idx < 576; idx += 512) ws[idx] = w[co * 576 + idx];
    __syncthreads();
    int og  = tid & 63;
    int grp = tid >> 6;
    int h = og >> 2, wq = og & 3;
    float ax = 0.f, ay = 0.f, az = 0.f, aw = 0.f;
    #pragma unroll 4
    for (int c2 = 0; c2 < 8; ++c2) {
        int ci = grp * 8 + c2;
        const float* row = x + ci * 4096 + d * 256;
        const float* wc  = ws + ci * 9;
        #pragma unroll
        for (int dh = 0; dh < 3; ++dh) {
            int hh = h + dh - 1;
            if (hh < 0 || hh > 15) continue;
            const float* r = row + hh * 16 + wq * 4;
            float4 q0 = *(const float4*)r;
            float lm = (wq > 0) ? r[-1] : 0.f;
            float rp = (wq < 3) ? r[4]  : 0.f;
            float wL = wc[dh * 3 + 0], wM = wc[dh * 3 + 1], wR = wc[dh * 3 + 2];
            ax += wL * lm   + wM * q0.x + wR * q0.y;
            ay += wL * q0.x + wM * q0.y + wR * q0.z;
            az += wL * q0.y + wM * q0.z + wR * q0.w;
            aw += wL * q0.z + wM * q0.w + wR * rp;
        }
    }
    float4 part = {ax, ay, az, aw};
    *(float4*)&red[grp][og * 4] = part;
    __syncthreads();
    if (tid < 256) {
        float s = b[co];
        #pragma unroll
        for (int g = 0; g < 8; ++g) s += red[g][tid];
        y[co * 4096 + d * 256 + tid] = s;
    }
}

// ---------------------------------------------------------------------------
// Stage 2+3: spectral-conv + QKV as MFMA GEMM.
// Block = (d, pos-eighth, oc-third): 384 blocks. M=64, N=32, K=192.
// Staging: 12 loads/thread; LDS 12.25 KB.
#define BTP 196   // Bt row stride in bf16 (392 B: 8B-aligned)
__global__ __launch_bounds__(512, 2) void qkv_mfma_kernel(
        const float* __restrict__ y1, const unsigned short* __restrict__ wfb,
        const float* __restrict__ bfv,
        unsigned short* __restrict__ qb, unsigned short* __restrict__ kb,
        unsigned short* __restrict__ vtb) {
    __shared__ __align__(16) unsigned short Bt[32 * BTP];    // [pos][k], 12.25 KB
    int bI  = blockIdx.x;            // 384 = 16 d x 8 pq x 3 ocg
    int ocg = bI % 3;                // 0=q 1=k 2=v
    int pq  = (bI / 3) & 7;
    int d   = bI / 24;
    int tid = threadIdx.x;

    // ---- stage im2col slab: Bt[px][ci*3+t] = y1[ci][d+t-1][pq*32+px]
    {
        int px  = tid & 31;
        int cig = tid >> 5;          // 0..15 (4 ci each)
        const float* yb = y1 + d * 256 + pq * 32 + px;
        #pragma unroll
        for (int cc = 0; cc < 4; ++cc) {
            int ci = cig * 4 + cc;
            const float* yc = yb + ci * 4096;
            #pragma unroll
            for (int t = 0; t < 3; ++t) {
                float v = 0.f;
                if (!((d == 0 && t == 0) || (d == 15 && t == 2)))
                    v = yc[(t - 1) * 256];
                Bt[px * BTP + ci * 3 + t] = f2bf(v);
            }
        }
    }

    int wv = tid >> 6, lane = tid & 63;
    int quad = lane >> 4, l15 = lane & 15;
    int Mt = wv >> 1;                // 0..3 (= head)
    int nt = wv & 1;                 // N-tile (16 pos)

    // ---- A-fragments: A[m=l15][k=quad*8+j], 6 K-steps
    short8 af[6];
    {
        const unsigned short* ab = wfb + (ocg * 64 + Mt * 16 + l15) * 192 + quad * 8;
        #pragma unroll
        for (int ks = 0; ks < 6; ++ks) af[ks] = *(const short8*)(ab + ks * 32);
    }
    float bias[4];
    #pragma unroll
    for (int r = 0; r < 4; ++r) bias[r] = bfv[ocg * 64 + Mt * 16 + quad * 4 + r];

    __syncthreads();

    float4v czero = {0.f, 0.f, 0.f, 0.f};
    float4v acc = czero;
    {
        const unsigned short* brow = Bt + (nt * 16 + l15) * BTP + quad * 8;
        #pragma unroll
        for (int ks = 0; ks < 6; ++ks) {
            short4v lo = *(const short4v*)(brow + ks * 32);
            short4v hi = *(const short4v*)(brow + ks * 32 + 4);
            short8 bf8 = {lo[0], lo[1], lo[2], lo[3], hi[0], hi[1], hi[2], hi[3]};
            acc = __builtin_amdgcn_mfma_f32_16x16x32_bf16(af[ks], bf8, acc, 0, 0, 0);
        }
    }

    // ---- epilogue: C row = oc_local (quad*4+r), col = pos (l15)
    {
        int p = d * 256 + pq * 32 + nt * 16 + l15;
        if (ocg == 2) {
            int h = (p >> 4) & 15, w0 = p & 15;
            int kap = 8 * (w0 >> 2) + 4 * (h & 1) + (w0 & 3);
            unsigned short* dst = vtb + ((Mt * 16 + d) * 8 + (h >> 1)) * 512
                                      + (quad * 4) * 32 + kap;
            #pragma unroll
            for (int r = 0; r < 4; ++r) dst[r * 32] = f2bf(acc[r] + bias[r]);
        } else {
            unsigned short* dst = (ocg == 0 ? qb : kb) + Mt * 65536 + p * 16 + quad * 4;
            unsigned t0 = (unsigned)f2bf(acc[0] + bias[0])
                        | ((unsigned)f2bf(acc[1] + bias[1]) << 16);
            unsigned t1 = (unsigned)f2bf(acc[2] + bias[2])
                        | ((unsigned)f2bf(acc[3] + bias[3]) << 16);
            *(unsigned*)dst = t0;
            *(unsigned*)(dst + 2) = t1;
        }
    }
}

// ---------------------------------------------------------------------------
// Stage 4: retention attention via MFMA. r11 changes: register prefetch of
// the next K/V slab (overlaps global latency with compute), exp2 with log2e
// folded into wd[], round-half bf16 packing in the P inner loop.
__global__ __launch_bounds__(512, 2) void attn_kernel(
        const unsigned short* __restrict__ qb, const unsigned short* __restrict__ kb,
        const unsigned short* __restrict__ vtb, const float* __restrict__ gamma,
        float* __restrict__ ao0, float* __restrict__ ao1,
        float* __restrict__ ao2, float* __restrict__ ao3) {
    __shared__ __align__(16) unsigned short ksh[4096];   // [n][o][d16] bf16, 8 KB
    __shared__ __align__(16) unsigned short vsh[4096];   // [np][dim][kappa32], 8 KB
    __shared__ float gp[32];
    int tid = threadIdx.x;
    int bI = blockIdx.x;
    int head = bI >> 7;                 // 4
    int mg   = (bI >> 5) & 3;           // 4 m-quarters
    int oct  = bI & 31;                 // 32 q-octets per head

    if (tid < 32) {
        float g = 1.f / (1.f + __expf(-gamma[0]));
        gp[tid] = __powf(g, (float)tid);
    }

    int wv = tid >> 6, lane = tid & 63;
    int quad = lane >> 4, l15 = lane & 15;
    int t = oct * 8 + wv;               // tile index 0..255 (= i*16 + j)
    int i = t >> 4, j = t & 15;

    short8 zero8 = {0, 0, 0, 0, 0, 0, 0, 0};
    float4v czero = {0.f, 0.f, 0.f, 0.f};

    short8 qf = zero8;
    if (quad < 2)
        qf = *(const short8*)(qb + head * 65536 + (t * 16 + l15) * 16 + quad * 8);

    // prefetch first slab while gp settles
    const unsigned short* kbh = kb  + head * 65536 + mg * 4 * 4096;
    const unsigned short* vbh = vtb + head * 65536 + mg * 4 * 4096;   // == (head*16+mg*4)*4096
    float4 kpre = ((const float4*)kbh)[tid];
    float4 vpre = ((const float4*)vbh)[tid];

    __syncthreads();                    // gp ready
    float wd[4];
    #pragma unroll
    for (int r = 0; r < 4; ++r)
        wd[r] = gp[abs(l15 - (quad * 4 + r))] * 1.4426950408889634f;   // log2(e) folded

    float4v O = czero;

    for (int mm = 0; mm < 4; ++mm) {
        int m = mg * 4 + mm;
        __syncthreads();                // previous slab fully consumed
        ((float4*)ksh)[tid] = kpre;
        ((float4*)vsh)[tid] = vpre;
        __syncthreads();
        if (mm < 3) {                   // issue next-slab loads before compute
            kpre = ((const float4*)(kbh + (mm + 1) * 4096))[tid];
            vpre = ((const float4*)(vbh + (mm + 1) * 4096))[tid];
        }

        int eim = abs(i - m);
        #pragma unroll
        for (int np = 0; np < 8; ++np) {
            union { unsigned u[4]; short8 s8; } a2u;
            #pragma unroll
            for (int s = 0; s < 2; ++s) {
                int n = np * 2 + s;
                short8 a1 = zero8;
                if (quad < 2)
                    a1 = *(const short8*)(ksh + n * 256 + l15 * 16 + quad * 8);
                float4v d1 = __builtin_amdgcn_mfma_f32_16x16x32_bf16(a1, qf, czero, 0, 0, 0);
                float smn = gp[eim + abs(j - n)];        // wave-uniform broadcast
                float e0 = __builtin_amdgcn_exp2f(d1[0] * smn * wd[0]);
                float e1 = __builtin_amdgcn_exp2f(d1[1] * smn * wd[1]);
                float e2 = __builtin_amdgcn_exp2f(d1[2] * smn * wd[2]);
                float e3 = __builtin_amdgcn_exp2f(d1[3] * smn * wd[3]);
                float sm = e0 + e1 + e2 + e3;
                sm += __shfl_xor(sm, 16);
                sm += __shfl_xor(sm, 32);
                float inv = __builtin_amdgcn_rcpf(sm);
                union { float f; unsigned u; } p0, p1, p2, p3;
                p0.f = e0 * inv; p1.f = e1 * inv;
                p2.f = e2 * inv; p3.f = e3 * inv;
                // round-half bf16 packing (2 values -> 1 u32), 5 ops/pair
                a2u.u[s * 2]     = ((p0.u + 0x8000u) >> 16) | ((p1.u + 0x8000u) & 0xFFFF0000u);
                a2u.u[s * 2 + 1] = ((p2.u + 0x8000u) >> 16) | ((p3.u + 0x8000u) & 0xFFFF0000u);
            }
            short8 b2 = *(const short8*)(vsh + np * 512 + l15 * 32 + quad * 8);
            O = __builtin_amdgcn_mfma_f32_16x16x32_bf16(a2u.s8, b2, O, 0, 0, 0);
        }
    }

    float* aop = (mg == 0) ? ao0 : ((mg == 1) ? ao1 : ((mg == 2) ? ao2 : ao3));
    float4 ov = {O[0], O[1], O[2], O[3]};
    *(float4*)(aop + (head * 16 + l15) * 4096 + t * 16 + quad * 4) = ov;
}

// ---------------------------------------------------------------------------
// Stage 5: projection as MFMA GEMM. Block = (d, pos-16th): 256 blocks x 256
// thr. M=64, N=16, K=64. Partials summed during staging (16 loads/thread).
#define PTP 68    // Bt row stride bf16 (136 B: 8B-aligned)
__global__ __launch_bounds__(256) void proj_mfma_kernel(
        const float* __restrict__ ao0, const float* __restrict__ ao1,
        const float* __restrict__ ao2, const float* __restrict__ ao3,
        const float* __restrict__ w, const float* __restrict__ b,
        float* __restrict__ out) {
    __shared__ __align__(16) unsigned short Bt[16 * PTP];    // [pos][ci], 2.2 KB
    int d   = blockIdx.x >> 4;
    int p16 = blockIdx.x & 15;
    int tid = threadIdx.x;               // 256

    {   // stage: sum 4 partials -> bf16 Bt[px][ci]
        int px = tid & 15, cig = tid >> 4;        // cig 0..15 (4 ci each)
        int gbase = d * 256 + p16 * 16 + px;
        #pragma unroll
        for (int cc = 0; cc < 4; ++cc) {
            int ci = cig * 4 + cc;
            int ga = ci * 4096 + gbase;
            float v = ao0[ga] + ao1[ga] + ao2[ga] + ao3[ga];
            Bt[px * PTP + ci] = f2bf(v);
        }
    }
    __syncthreads();

    int wv = tid >> 6, lane = tid & 63;  // 4 waves: wv = M-tile
    int quad = lane >> 4, l15 = lane & 15;
    float4v czero = {0.f, 0.f, 0.f, 0.f};
    float4v acc = czero;

    short8 af[2];
    const float* wsrc = w + (wv * 16 + l15) * 64 + quad * 8;
    #pragma unroll
    for (int ks = 0; ks < 2; ++ks) {
        float4 wa = *(const float4*)(wsrc + ks * 32);
        float4 wb = *(const float4*)(wsrc + ks * 32 + 4);
        short8 a8 = {(short)f2bf(wa.x), (short)f2bf(wa.y), (short)f2bf(wa.z),
                     (short)f2bf(wa.w), (short)f2bf(wb.x), (short)f2bf(wb.y),
                     (short)f2bf(wb.z), (short)f2bf(wb.w)};
        af[ks] = a8;
    }
    const unsigned short* brow = Bt + l15 * PTP + quad * 8;
    #pragma unroll
    for (int ks = 0; ks < 2; ++ks) {
        short4v lo = *(const short4v*)(brow + ks * 32);
        short4v hi = *(const short4v*)(brow + ks * 32 + 4);
        short8 bf8 = {lo[0], lo[1], lo[2], lo[3], hi[0], hi[1], hi[2], hi[3]};
        acc = __builtin_amdgcn_mfma_f32_16x16x32_bf16(af[ks], bf8, acc, 0, 0, 0);
    }

    int p = d * 256 + p16 * 16 + l15;
    #pragma unroll
    for (int r = 0; r < 4; ++r) {
        int oc = wv * 16 + quad * 4 + r;
        out[oc * 4096 + p] = acc[r] + b[oc];
    }
}

// ---------------------------------------------------------------------------
extern "C" void kernel_launch(void* const* d_in, const int* in_sizes, int n_in,
                              void* d_out, int out_size, void* d_ws, size_t ws_size,
                              hipStream_t stream) {
    const float* x      = (const float*)d_in[0];
    const float* gamma  = (const float*)d_in[1];
    const float* w_sp   = (const float*)d_in[2];
    const float* b_sp   = (const float*)d_in[3];
    const float* w_spec = (const float*)d_in[4];
    const float* b_spec = (const float*)d_in[5];
    const float* w_qkv  = (const float*)d_in[6];
    const float* b_qkv  = (const float*)d_in[7];
    const float* w_proj = (const float*)d_in[8];
    const float* b_proj = (const float*)d_in[9];
    float* out = (float*)d_out;

    float* ws = (float*)d_ws;
    float* y1  = ws;                         // [64][4096] f32; reused as ao0
    unsigned short* wfb = (unsigned short*)(ws + CN);   // [192][192] bf16
    float* bfv = ws + CN + 20480;            // [192] fused bias f32
    unsigned short* qb  = (unsigned short*)(ws + 2 * CN);            // 512 KB bf16
    unsigned short* kb  = (unsigned short*)(ws + 2 * CN + CN / 2);   // 512 KB bf16
    unsigned short* vtb = (unsigned short*)(ws + 3 * CN);            // 512 KB bf16
    float* ao0 = y1;                         // safe: y1 consumed by qkv_mfma
    float* ao1 = ws + 3 * CN + CN / 2;       // [64][4096] partial (m 4..7)
    float* ao2 = ws + 4 * CN + CN / 2;       // [64][4096] partial (m 8..11)
    float* ao3 = ws + 5 * CN + CN / 2;       // [64][4096] partial (m 12..15)

    conv_sp_wfuse_kernel<<<1096, 512, 0, stream>>>(x, w_sp, b_sp, y1,
                                                   w_spec, b_spec, w_qkv, b_qkv,
                                                   wfb, bfv);
    qkv_mfma_kernel <<< 384, 512, 0, stream>>>(y1, wfb, bfv, qb, kb, vtb);
    attn_kernel     <<< 512, 512, 0, stream>>>(qb, kb, vtb, gamma, ao0, ao1, ao2, ao3);
    proj_mfma_kernel<<< 256, 256, 0, stream>>>(ao0, ao1, ao2, ao3, w_proj, b_proj, out);
}